// Round 5
// baseline (560.838 us; speedup 1.0000x reference)
//
#include <hip/hip_runtime.h>
#include <stdint.h>

#define BB 8
#define CC 256
#define HDIM 128
#define NHW 4096
#define MM 10
#define OUTN (BB*CC*NHW)   // 2097152

typedef uint32_t u32;
typedef unsigned short u16;
using f32x4 = __attribute__((ext_vector_type(4))) float;
using bfv8  = __attribute__((ext_vector_type(8))) short;
using bfv4  = __attribute__((ext_vector_type(4))) short;

#if __has_builtin(__builtin_amdgcn_mfma_f32_16x16x16bf16_1k)
#define HAS16 1
#else
#define HAS16 0
#endif

__device__ __forceinline__ u16 f2bf(float f){
  union { float f; u32 u; } v; v.f = f;
  u32 u = v.u;
  u32 r = (u + 0x7fffu + ((u >> 16) & 1u)) >> 16;
  return (u16)r;
}

__device__ __forceinline__ float bf2f(u16 h){
  union { u32 u; float f; } v; v.u = ((u32)h) << 16; return v.f;
}

__device__ __forceinline__ f32x4 mfma16(bfv8 a, bfv8 b, f32x4 c){
  return __builtin_amdgcn_mfma_f32_16x16x32_bf16(a, b, c, 0, 0, 0);
}

__device__ __forceinline__ u32 cvtpk(float a, float b){
  u32 r; asm("v_cvt_pk_bf16_f32 %0, %1, %2" : "=v"(r) : "v"(a), "v"(b)); return r;
}

__device__ __forceinline__ float fexp2(float x){
#if __has_builtin(__builtin_amdgcn_exp2f)
  return __builtin_amdgcn_exp2f(x);
#else
  return exp2f(x);
#endif
}

// async global->LDS, 16B per lane; lds dst is wave-uniform base (+lane*16 implicit)
__device__ __forceinline__ void gload16(const void* g, void* l){
  __builtin_amdgcn_global_load_lds((const __attribute__((address_space(1))) unsigned int*)g,
                                   (__attribute__((address_space(3))) unsigned int*)l, 16, 0, 0);
}

// ---------------- K0: key (B,C,HW) f32 -> keyT (B,HW,C) bf16, LDS tile transpose ----------------
__global__ __launch_bounds__(256) void k0_keyt(const float* __restrict__ key, u16* __restrict__ keyT){
  __shared__ u16 sm[64][73];
  int blk = blockIdx.x;             // 2048 = b + 8*(ct + 4*nt)
  int b = blk & 7; int r = blk >> 3; int ct = r & 3; int nt = r >> 2;
  int n0 = nt*64, c0 = ct*64;
  int t = threadIdx.x; int nl = t & 63; int cl0 = t >> 6;
#pragma unroll
  for (int i = 0; i < 16; ++i){
    int cl = i*4 + cl0;
    sm[cl][nl] = f2bf(key[(size_t)(b*CC + c0 + cl)*NHW + n0 + nl]);
  }
  __syncthreads();
#pragma unroll
  for (int i = 0; i < 2; ++i){
    int j = i*256 + t; int nl2 = j >> 3; int c8 = j & 7;
    __align__(16) u16 tmp[8];
#pragma unroll
    for (int k = 0; k < 8; ++k) tmp[k] = sm[c8*8 + k][nl2];
    *(uint4*)&keyT[(size_t)(b*NHW + n0 + nl2)*CC + c0 + c8*8] = *(uint4*)tmp;
  }
}

// ---------------- K0b: weights -> bf16, zero stats + protos ----------------
__global__ __launch_bounds__(256) void k0b_w(const float* __restrict__ Wth, const float* __restrict__ Wph,
                                             const float* __restrict__ Wg, const float* __restrict__ Wpc,
                                             const float* __restrict__ Wo,
                                             u16* __restrict__ Wbf, u16* __restrict__ Wobf,
                                             float* __restrict__ stats, float* __restrict__ protos){
  int flat = blockIdx.x*256 + threadIdx.x;
  if (flat < 1540) stats[flat] = 0.f;
  if (flat < BB*MM*HDIM) protos[flat] = 0.f;
  int base = flat*4;
  u16 o4[4]; uint2 pk;
  if (base < 512*256){
    int o = base >> 8, c = base & 255;
    const float* srcs[4] = {Wth, Wph, Wg, Wpc};
    const float* sp = srcs[o >> 7] + (size_t)(o & 127)*256 + c;
#pragma unroll
    for (int j=0;j<4;++j) o4[j] = f2bf(sp[j]);
    pk.x = (u32)o4[0] | ((u32)o4[1]<<16); pk.y = (u32)o4[2] | ((u32)o4[3]<<16);
    *(uint2*)&Wbf[base] = pk;
  } else {
    int b2 = base - 512*256;           // Wobf flat, 256*128
    const float* sp = Wo + b2;
#pragma unroll
    for (int j=0;j<4;++j) o4[j] = f2bf(sp[j]);
    pk.x = (u32)o4[0] | ((u32)o4[1]<<16); pk.y = (u32)o4[2] | ((u32)o4[3]<<16);
    *(uint2*)&Wobf[b2] = pk;
  }
}

// ---------------- K1: fused 4-conv MFMA GEMM, 4 waves (2n x 2ob), W prefetch ----------------
// theta output pre-scaled by log2(e) so k3 can use exp2.
__global__ __launch_bounds__(256) void k1_conv4(const u16* __restrict__ keyT, const u16* __restrict__ Wbf,
    const float* __restrict__ bth, const float* __restrict__ bph, const float* __restrict__ bg, const float* __restrict__ bpc,
    u16* __restrict__ thetaT, u16* __restrict__ phiT, u16* __restrict__ gN, float* __restrict__ pcraw)
{
  __shared__ __align__(16) u16 lds[64*256];     // 32KB, 16B-word swizzled: phys = logical ^ (row&7)
  int blk = blockIdx.x;                          // b + 8*nt, grid 512
  int b = blk & 7; int nt = blk >> 3; int n0 = nt*64;
  int t = threadIdx.x; int w = t >> 6; int l = t & 63;
  int l15 = l & 15, l4 = l >> 4;
  const u16* src = keyT + (size_t)(b*NHW + n0)*CC;
#pragma unroll
  for (int i = 0; i < 8; ++i){
    int c = w*8 + i;
    int row = c*2 + (l >> 5);
    int wl = (l & 31) ^ (row & 7);
    gload16(src + (size_t)row*256 + wl*8, &lds[c*512]);
  }
  __syncthreads();
  int wn = w & 1, wo = w >> 1;
  bfv8 a[2][8];
#pragma unroll
  for (int nb = 0; nb < 2; ++nb)
#pragma unroll
    for (int kb = 0; kb < 8; ++kb){
      int row = wn*32 + nb*16 + l15;
      int wd = (kb*4 + l4) ^ (row & 7);
      a[nb][kb] = *(const bfv8*)&lds[row*256 + wd*8];
    }
  const float* bias[4] = {bth, bph, bg, bpc};
  const u16* wpbase = Wbf + (size_t)(wo*16*16 + l15)*256 + l4*8;
  bfv8 wc[8], wnx[8];
#pragma unroll
  for (int kb = 0; kb < 8; ++kb) wc[kb] = *(const bfv8*)&wpbase[kb*32];
  for (int ob = 0; ob < 16; ++ob){
    if (ob < 15){
      const u16* wp = wpbase + (size_t)(ob+1)*16*256;
#pragma unroll
      for (int kb = 0; kb < 8; ++kb) wnx[kb] = *(const bfv8*)&wp[kb*32];
    }
    f32x4 acc[2] = {{0,0,0,0},{0,0,0,0}};
#pragma unroll
    for (int kb = 0; kb < 8; ++kb){
      acc[0] = mfma16(a[0][kb], wc[kb], acc[0]);
      acc[1] = mfma16(a[1][kb], wc[kb], acc[1]);
    }
    int obg = wo*16 + ob;
    int seg = obg >> 3;
    int oo = (obg & 7)*16 + l15;
    float bv = bias[seg][oo];
#pragma unroll
    for (int nb = 0; nb < 2; ++nb)
#pragma unroll
      for (int rr = 0; rr < 4; ++rr){
        int n = n0 + wn*32 + nb*16 + l4*4 + rr;
        float v = acc[nb][rr] + bv;
        size_t off = ((size_t)(b*NHW + n))*HDIM + oo;
        if      (seg == 0) thetaT[off] = f2bf(v * 1.44269504f);
        else if (seg == 1) phiT[off]   = f2bf(v);
        else if (seg == 2) gN[off]     = f2bf(v);
        else               pcraw[off]  = v;
      }
#pragma unroll
    for (int kb = 0; kb < 8; ++kb) wc[kb] = wnx[kb];
  }
}

// ---------------- K1b: gN (B,HW,HD) -> gT (B,HD,HW) bf16 ----------------
__global__ __launch_bounds__(256) void k1b_gt(const u16* __restrict__ gN, u16* __restrict__ gT){
  __shared__ __align__(16) u16 lds[64][72];
  int blk = blockIdx.x;               // 1024 = b + 8*(nt + 64*dt)
  int b = blk & 7; int r = blk >> 3; int nt = r & 63; int dt = r >> 6;
  int n0 = nt*64, d0 = dt*64;
  int t = threadIdx.x;
#pragma unroll
  for (int i = 0; i < 2; ++i){
    int seg = i*256 + t; int row = seg >> 3; int sg = seg & 7;
    *(uint4*)&lds[row][sg*8] = *(const uint4*)&gN[(size_t)(b*NHW + n0 + row)*HDIM + d0 + sg*8];
  }
  __syncthreads();
  int dr = t >> 2, ns = (t & 3)*16;
  __align__(16) u16 tmp[16];
#pragma unroll
  for (int j = 0; j < 16; ++j) tmp[j] = lds[ns + j][dr];
  u16* dst = gT + (size_t)(b*HDIM + d0 + dr)*NHW + n0 + ns;
  *(uint4*)&dst[0] = *(uint4*)&tmp[0];
  *(uint4*)&dst[8] = *(uint4*)&tmp[8];
}

// ---------------- K2: pc BN stats ----------------
__global__ __launch_bounds__(256) void k2_pcstats(const float* __restrict__ pcraw, float* __restrict__ stats){
  int blk = blockIdx.x;                // 256 = b*32 + ch
  int b = blk >> 5; int ch = blk & 31; int n0 = ch*128;
  int t = threadIdx.x; int d = t & 127; int j = t >> 7;
  float s = 0, ss = 0;
  const float* p = pcraw + (size_t)(b*NHW + n0)*HDIM;
  for (int i = 0; i < 64; ++i){ float v = p[(size_t)(i*2 + j)*HDIM + d]; s += v; ss += v*v; }
  __shared__ float red[2][256];
  red[0][t] = s; red[1][t] = ss;
  __syncthreads();
  if (t < 128){
    atomicAdd(&stats[d],       red[0][t] + red[0][t+128]);
    atomicAdd(&stats[128 + d], red[1][t] + red[1][t+128]);
  }
}

// ---------------- K2b: keyf = relu(BN(pcraw)) — BN params computed inline ----------------
__global__ __launch_bounds__(256) void k2b_keyf(const float* __restrict__ pcraw, const float* __restrict__ stats,
                                                const float* __restrict__ gamma, const float* __restrict__ beta,
                                                float* __restrict__ keyf){
  int idx = blockIdx.x*256 + threadIdx.x;
  int base = idx*4; int d0 = base & 127;
  f32x4 v = *(const f32x4*)&pcraw[base];
  f32x4 o;
#pragma unroll
  for (int j = 0; j < 4; ++j){
    int d = d0 + j;
    float mean = stats[d] * (1.f/32768.f);
    float var  = stats[128+d] * (1.f/32768.f) - mean*mean;
    if (var < 0.f) var = 0.f;
    float rstd = rsqrtf(var + 1e-5f);
    float x = (v[j] - mean) * rstd * gamma[d] + beta[d];
    o[j] = x > 0.f ? x : 0.f;
  }
  *(f32x4*)&keyf[base] = o;
}

// ---------------- K3: flash attention v4 ----------------
// 64 q/wave (256 q/block), swapped QK (mfma(K,Q)) so each lane holds 4 consecutive m per q;
// P packed in-register via v_cvt_pk_bf16_f32 and fed to 16x16x16 PV MFMA (no P LDS).
// fixed-max softmax via exp2 (theta pre-scaled by log2 e); KV-split=4; double-buffered K/V.
__global__ __launch_bounds__(256, 2) void k3_attn(const u16* __restrict__ thetaT, const u16* __restrict__ phiT,
                                               const u16* __restrict__ gT,
                                               u16* __restrict__ nl0, u16* __restrict__ nl1,
                                               u16* __restrict__ nl2, u16* __restrict__ nl3,
                                               float* __restrict__ lsumP){
  __shared__ __align__(16) u16 K2[2][32*128];   // 2 x 8KB, m-major rows 256B, slot^ (row&7) swizzle
  __shared__ __align__(16) u16 V2[2][128*32];   // 2 x 8KB, d-major rows 64B, slot^(row&3) swizzle
#if !HAS16
  __shared__ __align__(16) u16 P[4][64*40];     // fallback P: per wave 64q x 32m pad 40
#endif
  int blk = blockIdx.x;             // b + 8*(qt + 16*split); b = XCD id
  int b = blk & 7; int qt = (blk >> 3) & 15; int split = blk >> 7;
  int n0 = qt*256;
  int t = threadIdx.x; int w = t >> 6; int l = t & 63;
  int l15 = l & 15, l4 = l >> 4;
  // Q fragments (B operand): qf[qb][kb]
  bfv8 qf[4][4];
#pragma unroll
  for (int qb = 0; qb < 4; ++qb){
    const u16* qp = thetaT + (size_t)(b*NHW + n0 + w*64 + qb*16 + l15)*HDIM + l4*8;
#pragma unroll
    for (int kb = 0; kb < 4; ++kb) qf[qb][kb] = *(const bfv8*)&qp[kb*32];
  }
  float lsum[4];
  f32x4 acco[4][8];
#pragma unroll
  for (int qb = 0; qb < 4; ++qb){
    lsum[qb] = 0.f;
#pragma unroll
    for (int db = 0; db < 8; ++db) acco[qb][db] = {0,0,0,0};
  }
  const u16* Kg = phiT + (size_t)b*NHW*HDIM;
  const u16* Vg = gT   + (size_t)b*HDIM*NHW;
  int mt0 = split*32;               // 32 tiles of 32 m each

#define STAGE(bf, mt) {                                                        \
    int m0 = (mt)*32;                                                          \
  _Pragma("unroll")                                                            \
    for (int i = 0; i < 2; ++i){                                               \
      int c = w*2 + i;                                                         \
      int row = c*4 + (l >> 4);                                                \
      int wl = (l & 15) ^ (row & 7);                                           \
      gload16(Kg + (size_t)(m0 + row)*HDIM + wl*8, &K2[bf][c*512]);            \
    }                                                                          \
  _Pragma("unroll")                                                            \
    for (int i = 0; i < 2; ++i){                                               \
      int c = w*2 + i;                                                         \
      int row = c*16 + (l >> 2);                                               \
      int wl = (l & 3) ^ (row & 3);                                            \
      gload16(Vg + (size_t)row*NHW + m0 + wl*8, &V2[bf][c*512]);               \
    }                                                                          \
  }

  STAGE(0, mt0);
  __syncthreads();
  int cur = 0;
  for (int it = 0; it < 32; ++it){
    if (it < 31) STAGE(cur^1, mt0 + it + 1);
    // QK^T swapped: A=K (rows m), B=Q (cols q) -> lane holds P[q=l15][m = mb*16 + l4*4 + rr]
    f32x4 s[2][4];
#pragma unroll
    for (int mb = 0; mb < 2; ++mb)
#pragma unroll
      for (int qb = 0; qb < 4; ++qb) s[mb][qb] = {0,0,0,0};
    __builtin_amdgcn_s_setprio(1);
#pragma unroll
    for (int kb = 0; kb < 4; ++kb){
#pragma unroll
      for (int mb = 0; mb < 2; ++mb){
        int krow = mb*16 + l15;
        int kw = (kb*4 + l4) ^ (krow & 7);
        bfv8 kf = *(const bfv8*)&K2[cur][krow*128 + kw*8];
#pragma unroll
        for (int qb = 0; qb < 4; ++qb)
          s[mb][qb] = mfma16(kf, qf[qb][kb], s[mb][qb]);
      }
    }
    __builtin_amdgcn_s_setprio(0);
#if HAS16
    // softmax: p = exp2(s); pack 4 consecutive m into bf16x4 (A-frag of 16x16x16 MFMA)
    bfv4 pa[2][4];
#pragma unroll
    for (int mb = 0; mb < 2; ++mb)
#pragma unroll
      for (int qb = 0; qb < 4; ++qb){
        float p0 = fexp2(s[mb][qb][0]);
        float p1 = fexp2(s[mb][qb][1]);
        float p2 = fexp2(s[mb][qb][2]);
        float p3 = fexp2(s[mb][qb][3]);
        lsum[qb] += (p0+p1)+(p2+p3);
        union { uint2 u; bfv4 v; } cv;
        cv.u.x = cvtpk(p0, p1); cv.u.y = cvtpk(p2, p3);
        pa[mb][qb] = cv.v;
      }
    // PV: A=P (rows q, k=m), B=V (cols d, k=m), K=16 per mfma
    __builtin_amdgcn_s_setprio(1);
#pragma unroll
    for (int db = 0; db < 8; ++db){
      int vrow = db*16 + l15;
#pragma unroll
      for (int mb = 0; mb < 2; ++mb){
        int sg = mb*2 + (l4 >> 1);
        int ph = ((sg ^ (vrow & 3))*8 + (l4 & 1)*4);
        bfv4 vf = *(const bfv4*)&V2[cur][vrow*32 + ph];
#pragma unroll
        for (int qb = 0; qb < 4; ++qb)
          acco[qb][db] = __builtin_amdgcn_mfma_f32_16x16x16bf16_1k(pa[mb][qb], vf, acco[qb][db], 0, 0, 0);
      }
    }
    __builtin_amdgcn_s_setprio(0);
#else
    // fallback: P through per-wave LDS, PV with 16x16x32
    u16* Pw = &P[w][0];
#pragma unroll
    for (int mb = 0; mb < 2; ++mb)
#pragma unroll
      for (int qb = 0; qb < 4; ++qb){
        float p0 = fexp2(s[mb][qb][0]);
        float p1 = fexp2(s[mb][qb][1]);
        float p2 = fexp2(s[mb][qb][2]);
        float p3 = fexp2(s[mb][qb][3]);
        lsum[qb] += (p0+p1)+(p2+p3);
        uint2 pk; pk.x = cvtpk(p0, p1); pk.y = cvtpk(p2, p3);
        *(uint2*)&Pw[(qb*16 + l15)*40 + mb*16 + l4*4] = pk;
      }
    bfv8 pa[4];
#pragma unroll
    for (int qb = 0; qb < 4; ++qb)
      pa[qb] = *(const bfv8*)&Pw[(qb*16 + l15)*40 + l4*8];
    __builtin_amdgcn_s_setprio(1);
#pragma unroll
    for (int db = 0; db < 8; ++db){
      int vrow = db*16 + l15;
      int vw = l4 ^ (vrow & 3);
      bfv8 vf = *(const bfv8*)&V2[cur][vrow*32 + vw*8];
#pragma unroll
      for (int qb = 0; qb < 4; ++qb)
        acco[qb][db] = mfma16(pa[qb], vf, acco[qb][db]);
    }
    __builtin_amdgcn_s_setprio(0);
#endif
    __syncthreads();                   // drains vmcnt -> staged buf ready; protects buf reuse
    cur ^= 1;
  }
#undef STAGE
  // epilogue: lsum per q = l15-lane; sum across the 4 quarters; write bf16 partial O + lsum
  u16* nlsaP = (split==0) ? nl0 : (split==1) ? nl1 : (split==2) ? nl2 : nl3;
#pragma unroll
  for (int qb = 0; qb < 4; ++qb){
    float v = lsum[qb];
    v += __shfl_xor(v, 16); v += __shfl_xor(v, 32);
    if (l < 16) lsumP[(size_t)(split*8 + b)*NHW + n0 + w*64 + qb*16 + l] = v;
#pragma unroll
    for (int rr = 0; rr < 4; ++rr){
      int n = n0 + w*64 + qb*16 + l4*4 + rr;
      u16* op = nlsaP + ((size_t)(b*NHW + n))*HDIM;
#pragma unroll
      for (int db = 0; db < 8; ++db)
        op[db*16 + l15] = f2bf(acco[qb][db][rr]);
    }
  }
}

// ---------------- K4: protos (unnormalized; softmax normalizer cancels in l2norm) ----------------
__global__ __launch_bounds__(256) void k4_protos(const float* __restrict__ keyf, const float* __restrict__ Wh,
                                                 float* __restrict__ protos){
  __shared__ float wh[10][128];
  __shared__ float e[128][12];
  __shared__ float pacc[10][128];
  int blk = blockIdx.x; int b = blk & 7; int ns = blk >> 3;   // 32 ns
  int n0 = ns*128;
  int t = threadIdx.x;
  for (int i = t; i < 1280; i += 256) wh[i>>7][i&127] = Wh[i];
  __syncthreads();
  const float* kf = keyf + ((size_t)b*NHW + n0)*HDIM;
  {
    int nn = t >> 1; int mh = (t & 1)*5;
    const f32x4* row = (const f32x4*)&kf[(size_t)nn*HDIM];
    float s5[5];
#pragma unroll
    for (int m = 0; m < 5; ++m) s5[m] = 0.f;
    for (int d4 = 0; d4 < 32; ++d4){
      f32x4 kv = row[d4];
#pragma unroll
      for (int m = 0; m < 5; ++m){
        f32x4 wv = *(const f32x4*)&wh[mh+m][d4*4];
        s5[m] += kv[0]*wv[0] + kv[1]*wv[1] + kv[2]*wv[2] + kv[3]*wv[3];
      }
    }
#pragma unroll
    for (int m = 0; m < 5; ++m) e[nn][mh+m] = __expf(s5[m]);
  }
  __syncthreads();
  int d = t & 127, j = t >> 7;
  float acc[10];
#pragma unroll
  for (int m = 0; m < 10; ++m) acc[m] = 0.f;
  for (int i = 0; i < 64; ++i){
    int n = j*64 + i;
    float kv = kf[(size_t)n*HDIM + d];
#pragma unroll
    for (int m = 0; m < 10; ++m) acc[m] += e[n][m]*kv;
  }
  if (j == 1){
#pragma unroll
    for (int m = 0; m < 10; ++m) pacc[m][d] = acc[m];
  }
  __syncthreads();
  if (j == 0){
#pragma unroll
    for (int m = 0; m < 10; ++m)
      atomicAdd(&protos[(size_t)(b*MM + m)*HDIM + d], acc[m] + pacc[m][d]);
  }
}

// ---------------- K5: normalize protos -> pnorm (own batch) + dis/cst losses ----------------
// Each block normalizes its own 10 rows + next batch's 10 rows locally (no cross-block race).
__global__ __launch_bounds__(128) void k5_pnloss(const float* __restrict__ protos, float* __restrict__ pnorm,
                                                 float* __restrict__ stats){
  __shared__ float pr[20][128];
  __shared__ float rd[2][2];
  int b = blockIdx.x;                // 8
  int t = threadIdx.x; int wv = t >> 6; int ln = t & 63;
  int nrows = (b < 7) ? 20 : 10;
  for (int r = wv; r < nrows; r += 2){
    int g = (r < 10) ? (b*10 + r) : ((b+1)*10 + (r-10));
    float v0 = protos[g*128 + ln];
    float v1 = protos[g*128 + 64 + ln];
    float ss = v0*v0 + v1*v1;
#pragma unroll
    for (int msk = 1; msk < 64; msk <<= 1) ss += __shfl_xor(ss, msk);
    float inv = 1.f / fmaxf(sqrtf(ss), 1e-12f);
    v0 *= inv; v1 *= inv;
    pr[r][ln] = v0; pr[r][64+ln] = v1;
    if (r < 10){ pnorm[g*128 + ln] = v0; pnorm[g*128 + 64 + ln] = v1; }
  }
  __syncthreads();
  int d = t;                         // 0..127
  float dacc = 0.f;
#pragma unroll
  for (int m1 = 0; m1 < 10; ++m1){
    float a = pr[m1][d];
#pragma unroll
    for (int m2 = 0; m2 < 10; ++m2){
      if (d >= m2 + 1){
        float df = a - pr[m2][d];
        float v = 1.f - df*df;
        if (v > 0.f) dacc += v;
      }
    }
  }
  float cacc = 0.f;
  if (b < 7){
#pragma unroll
    for (int m = 0; m < 10; ++m){
      float df = pr[10+m][d] - pr[m][d];
      cacc += df*df;
    }
  }
#pragma unroll
  for (int msk = 1; msk < 64; msk <<= 1){ dacc += __shfl_xor(dacc, msk); cacc += __shfl_xor(cacc, msk); }
  if (ln == 0){ rd[0][wv] = dacc; rd[1][wv] = cacc; }
  __syncthreads();
  if (t == 0){
    atomicAdd(&stats[1537], rd[0][0] + rd[0][1]);
    atomicAdd(&stats[1538], rd[1][0] + rd[1][1]);
  }
}

// ---------------- K6: score softmax, new_q, combine 4 nlsa splits (bf16), uq bf16, fea ----------------
// Row kept in registers: keyf read once; a[] overwrites kv[].
__global__ __launch_bounds__(128, 2) void k6_newq(const float* __restrict__ keyf, const float* __restrict__ pn,
                                              const u16* __restrict__ nl0, const u16* __restrict__ nl1,
                                              const u16* __restrict__ nl2, const u16* __restrict__ nl3,
                                              const float* __restrict__ lsumP,
                                              u16* __restrict__ uqbf, float* __restrict__ fea_acc){
  __shared__ float pnl[10][132];
  __shared__ float red[2];
  int blk = blockIdx.x;              // 256 = b + 8*nt
  int b = blk & 7; int nt = blk >> 3;
  int t = threadIdx.x;
  for (int i = t; i < 1280; i += 128) pnl[i>>7][i&127] = pn[(size_t)b*1280 + i];
  __syncthreads();
  int n = nt*128 + t;
  const float* kf = keyf + (size_t)(b*NHW + n)*HDIM;
  f32x4 kv[32];
#pragma unroll
  for (int d4 = 0; d4 < 32; ++d4) kv[d4] = *(const f32x4*)&kf[d4*4];
  float s[10];
#pragma unroll
  for (int m = 0; m < 10; ++m) s[m] = 0.f;
#pragma unroll
  for (int d4 = 0; d4 < 32; ++d4){
    f32x4 k = kv[d4];
#pragma unroll
    for (int m = 0; m < 10; ++m){
      f32x4 pv = *(const f32x4*)&pnl[m][d4*4];
      s[m] += k[0]*pv[0]+k[1]*pv[1]+k[2]*pv[2]+k[3]*pv[3];
    }
  }
  float mx = s[0]; int idx = 0;
#pragma unroll
  for (int m = 1; m < 10; ++m) if (s[m] > mx){ mx = s[m]; idx = m; }
  float S_ = 0, sp[10];
#pragma unroll
  for (int m = 0; m < 10; ++m){ float ev = __expf(s[m]-mx); sp[m] = ev; S_ += ev; }
  float invS = 1.f/S_;
#pragma unroll
  for (int m = 0; m < 10; ++m) sp[m] *= invS;
  float ssq = 0, fea = 0;
#pragma unroll
  for (int d4 = 0; d4 < 32; ++d4){
    f32x4 k = kv[d4];
    f32x4 a = {0,0,0,0};
#pragma unroll
    for (int m = 0; m < 10; ++m){
      f32x4 pv = *(const f32x4*)&pnl[m][d4*4];
      a[0] += sp[m]*pv[0]; a[1] += sp[m]*pv[1]; a[2] += sp[m]*pv[2]; a[3] += sp[m]*pv[3];
    }
    ssq += a[0]*a[0]+a[1]*a[1]+a[2]*a[2]+a[3]*a[3];
    f32x4 pb = *(const f32x4*)&pnl[idx][d4*4];
    float e0 = k[0]-pb[0], e1 = k[1]-pb[1], e2 = k[2]-pb[2], e3 = k[3]-pb[3];
    fea += e0*e0+e1*e1+e2*e2+e3*e3;
    kv[d4] = a;
  }
  float inv = 1.f / fmaxf(sqrtf(ssq), 1e-12f);
  float ls = lsumP[(size_t)b*NHW + n] + lsumP[(size_t)(8+b)*NHW + n]
           + lsumP[(size_t)(16+b)*NHW + n] + lsumP[(size_t)(24+b)*NHW + n];
  float invl = 1.f/ls;
  const u16* na0 = nl0 + (size_t)(b*NHW + n)*HDIM;
  const u16* na1 = nl1 + (size_t)(b*NHW + n)*HDIM;
  const u16* na2 = nl2 + (size_t)(b*NHW + n)*HDIM;
  const u16* na3 = nl3 + (size_t)(b*NHW + n)*HDIM;
  u16* uo = uqbf + (size_t)(b*NHW + n)*HDIM;
#pragma unroll
  for (int d4 = 0; d4 < 32; ++d4){
    uint2 r0 = *(const uint2*)&na0[d4*4];
    uint2 r1 = *(const uint2*)&na1[d4*4];
    uint2 r2 = *(const uint2*)&na2[d4*4];
    uint2 r3 = *(const uint2*)&na3[d4*4];
    u16 o4[4];
#pragma unroll
    for (int j = 0; j < 4; ++j){
      u32 word0 = (j < 2) ? r0.x : r0.y;  u32 word1 = (j < 2) ? r1.x : r1.y;
      u32 word2 = (j < 2) ? r2.x : r2.y;  u32 word3 = (j < 2) ? r3.x : r3.y;
      int sh = (j & 1)*16;
      float nv = bf2f((u16)(word0 >> sh)) + bf2f((u16)(word1 >> sh))
               + bf2f((u16)(word2 >> sh)) + bf2f((u16)(word3 >> sh));
      o4[j] = f2bf(kv[d4][j]*inv + nv*invl);
    }
    uint2 pk; pk.x = (u32)o4[0] | ((u32)o4[1]<<16); pk.y = (u32)o4[2] | ((u32)o4[3]<<16);
    *(uint2*)&uo[d4*4] = pk;
  }
#pragma unroll
  for (int msk = 1; msk < 64; msk <<= 1) fea += __shfl_xor(fea, msk);
  int wv = t >> 6;
  if ((t & 63) == 0) red[wv] = fea;
  __syncthreads();
  if (t == 0) atomicAdd(fea_acc, red[0] + red[1]);
}

// ---------------- K7: conv_o MFMA GEMM -> convo bf16 ----------------
__global__ __launch_bounds__(256) void k7_convo(const u16* __restrict__ uqbf, const u16* __restrict__ Wobf,
                                                const float* __restrict__ bo, u16* __restrict__ convo){
  __shared__ __align__(16) u16 lds[64*128];      // 16KB swizzled
  int blk = blockIdx.x;                          // b + 8*nt, grid 512
  int b = blk & 7; int nt = blk >> 3; int n0 = nt*64;
  int t = threadIdx.x; int w = t >> 6; int l = t & 63; int l15 = l&15, l4 = l>>4;
  const u16* src = uqbf + (size_t)(b*NHW + n0)*HDIM;
#pragma unroll
  for (int i = 0; i < 4; ++i){
    int c = w*4 + i;
    int row = c*4 + (l >> 4);
    int wl = (l & 15) ^ (row & 7);
    gload16(src + (size_t)row*128 + wl*8, &lds[c*512]);
  }
  __syncthreads();
  int wn = w & 1, wo = w >> 1;
  bfv8 a[2][4];
#pragma unroll
  for (int nb = 0; nb < 2; ++nb)
#pragma unroll
    for (int kb = 0; kb < 4; ++kb){
      int row = wn*32 + nb*16 + l15;
      int wd = (kb*4 + l4) ^ (row & 7);
      a[nb][kb] = *(const bfv8*)&lds[row*128 + wd*8];
    }
  const u16* wpbase = Wobf + (size_t)(wo*8*16 + l15)*128 + l4*8;
  bfv8 wc[4], wnx[4];
#pragma unroll
  for (int kb = 0; kb < 4; ++kb) wc[kb] = *(const bfv8*)&wpbase[kb*32];
  for (int ob = 0; ob < 8; ++ob){
    if (ob < 7){
      const u16* wp = wpbase + (size_t)(ob+1)*16*128;
#pragma unroll
      for (int kb = 0; kb < 4; ++kb) wnx[kb] = *(const bfv8*)&wp[kb*32];
    }
    f32x4 acc[2] = {{0,0,0,0},{0,0,0,0}};
#pragma unroll
    for (int kb = 0; kb < 4; ++kb){
      acc[0] = mfma16(a[0][kb], wc[kb], acc[0]);
      acc[1] = mfma16(a[1][kb], wc[kb], acc[1]);
    }
    int obg = wo*8 + ob;
    int oc = obg*16 + l15;
    float bv = bo[oc];
#pragma unroll
    for (int nb = 0; nb < 2; ++nb)
#pragma unroll
      for (int rr = 0; rr < 4; ++rr){
        int n = n0 + wn*32 + nb*16 + l4*4 + rr;
        convo[(size_t)(b*NHW + n)*CC + oc] = f2bf(acc[nb][rr] + bv);
      }
#pragma unroll
    for (int kb = 0; kb < 4; ++kb) wc[kb] = wnx[kb];
  }
}

// ---------------- K8: conv_o BN stats (bf16 in) ----------------
__global__ __launch_bounds__(256) void k8_ostats(const u16* __restrict__ convo, float* __restrict__ stats){
  int blk = blockIdx.x;                // 256 = b*32 + ch
  int b = blk >> 5; int ch = blk & 31; int n0 = ch*128;
  int t = threadIdx.x;
  float s = 0, ss = 0;
  const u16* p = convo + (size_t)(b*NHW + n0)*CC;
  for (int i = 0; i < 128; ++i){ float v = bf2f(p[(size_t)i*CC + t]); s += v; ss += v*v; }
  atomicAdd(&stats[512 + t], s);
  atomicAdd(&stats[768 + t], ss);
}

__global__ void k8a_fin(float* stats, float* dout){  // 256 threads
  int c = threadIdx.x;
  float mean = stats[512+c] * (1.f/32768.f);
  float var  = stats[768+c] * (1.f/32768.f) - mean*mean;
  if (var < 0.f) var = 0.f;
  stats[1024+c] = mean;
  stats[1280+c] = rsqrtf(var + 1e-5f);
  if (c == 0){
    dout[OUTN]   = stats[1536] * (1.f/4194304.f);
    dout[OUTN+1] = stats[1538] * (1.f/70.f);
    dout[OUTN+2] = stats[1537] * (2.f/90.f) * (1.f/1280.f);
  }
}

// ---------------- K9: out = relu(BN(convo)) + query (bf16 convo in) ----------------
__global__ __launch_bounds__(256) void k9_out(const u16* __restrict__ convo, const float* __restrict__ stats,
                                              const float* __restrict__ gamma, const float* __restrict__ beta,
                                              const float* __restrict__ query, float* __restrict__ dout){
  __shared__ __align__(16) float lds[32*260];
  int blk = blockIdx.x; int b = blk & 7; int nt = blk >> 3; int n0 = nt*32;
  int t = threadIdx.x;
  const u16* src = convo + (size_t)(b*NHW + n0)*CC;
#pragma unroll
  for (int i = 0; i < 4; ++i){
    int seg = i*256 + t; int row = seg >> 5; int sg = seg & 31;
    uint4 pk = *(const uint4*)&src[(size_t)row*CC + sg*8];
    float* dst = &lds[row*260 + sg*8];
    u32 ws[4] = {pk.x, pk.y, pk.z, pk.w};
#pragma unroll
    for (int j = 0; j < 4; ++j){
      dst[j*2]   = bf2f((u16)(ws[j] & 0xffffu));
      dst[j*2+1] = bf2f((u16)(ws[j] >> 16));
    }
  }
  __syncthreads();
  int nn = t & 31, og = t >> 5;
  for (int i = 0; i < 32; ++i){
    int oc = og*32 + i;
    float v = lds[nn*260 + oc];
    v = (v - stats[1024+oc]) * stats[1280+oc] * gamma[oc] + beta[oc];
    v = fmaxf(v, 0.f);
    size_t off = (size_t)(b*CC + oc)*NHW + n0 + nn;
    dout[off] = v + query[off];
  }
}

// ---------------- launch ----------------
extern "C" void kernel_launch(void* const* d_in, const int* in_sizes, int n_in,
                              void* d_out, int out_size, void* d_ws, size_t ws_size,
                              hipStream_t stream) {
  const float* key   = (const float*)d_in[0];
  const float* query = (const float*)d_in[1];
  const float* Wth = (const float*)d_in[2];
  const float* bth = (const float*)d_in[3];
  const float* Wph = (const float*)d_in[4];
  const float* bph = (const float*)d_in[5];
  const float* Wg  = (const float*)d_in[6];
  const float* bg  = (const float*)d_in[7];
  const float* Wpc = (const float*)d_in[8];
  const float* bpc = (const float*)d_in[9];
  const float* gpc = (const float*)d_in[10];
  const float* bepc= (const float*)d_in[11];
  const float* Wh  = (const float*)d_in[12];
  const float* Wo  = (const float*)d_in[13];
  const float* bo  = (const float*)d_in[14];
  const float* go  = (const float*)d_in[15];
  const float* beo = (const float*)d_in[16];

  char* ws = (char*)d_ws;
  u16*   keyT   = (u16*)  (ws + 0);          // 16MB [k0->k1]
  u16*   nlsa0  = (u16*)  (ws + 0);          // 8MB [k3->k6] (reuses keyT)
  u16*   nlsa1  = (u16*)  (ws + 8388608);    // 8MB [k3->k6]
  u16*   thetaT = (u16*)  (ws + 16777216);   // 8MB
  u16*   phiT   = (u16*)  (ws + 25165824);   // 8MB
  u16*   gN     = (u16*)  (ws + 33554432);   // 8MB [k1->k1b]
  float* lsum   = (float*)(ws + 33554432);   // 512KB [k3->k6] (reuses gN)
  u16*   gT     = (u16*)  (ws + 41943040);   // 8MB [k1b->k3]
  float* pcraw  = (float*)(ws + 50331648);   // 16MB [k1->k2b]
  u16*   nlsa2  = (u16*)  (ws + 50331648);   // 8MB [k3->k6] (reuses pcraw)
  u16*   nlsa3  = (u16*)  (ws + 58720256);   // 8MB [k3->k6]
  float* keyf   = (float*)(ws + 67108864);   // 16MB [k2b->k4,k6]
  u16*   uqbf   = (u16*)  (ws + 83886080);   // 8MB [k6->k7]
  u16*   convo  = (u16*)  (ws + 92274688);   // 16MB bf16 [k7->k8,k9]
  u16*   Wbf    = (u16*)  (ws + 109051904);  // 256KB
  u16*   Wobf   = (u16*)  (ws + 109314048);  // 64KB
  float* protos = (float*)(ws + 109379584);  // 40KB
  float* pnorm  = (float*)(ws + 109420544);  // 40KB
  float* stats  = (float*)(ws + 109461504);  // 8KB
  float* dout   = (float*)d_out;

  k0_keyt<<<2048,256,0,stream>>>(key, keyT);
  k0b_w<<<160,256,0,stream>>>(Wth, Wph, Wg, Wpc, Wo, Wbf, Wobf, stats, protos);
  k1_conv4<<<512,256,0,stream>>>(keyT, Wbf, bth, bph, bg, bpc, thetaT, phiT, gN, pcraw);
  k1b_gt<<<1024,256,0,stream>>>(gN, gT);
  k2_pcstats<<<256,256,0,stream>>>(pcraw, stats);
  k2b_keyf<<<4096,256,0,stream>>>(pcraw, stats, gpc, bepc, keyf);
  k3_attn<<<512,256,0,stream>>>(thetaT, phiT, gT, nlsa0, nlsa1, nlsa2, nlsa3, lsum);
  k4_protos<<<256,256,0,stream>>>(keyf, Wh, protos);
  k5_pnloss<<<8,128,0,stream>>>(protos, pnorm, stats);
  k6_newq<<<256,128,0,stream>>>(keyf, pnorm, nlsa0, nlsa1, nlsa2, nlsa3, lsum, uqbf, &stats[1536]);
  k7_convo<<<512,256,0,stream>>>(uqbf, Wobf, bo, convo);
  k8_ostats<<<256,256,0,stream>>>(convo, stats);
  k8a_fin<<<1,256,0,stream>>>(stats, dout);
  k9_out<<<1024,256,0,stream>>>(convo, stats, go, beo, query, dout);
}

// Round 7
// 406.841 us; speedup vs baseline: 1.3785x; 1.3785x over previous
//
#include <hip/hip_runtime.h>
#include <stdint.h>

#define BB 8
#define CC 256
#define HDIM 128
#define NHW 4096
#define MM 10
#define OUTN (BB*CC*NHW)   // 2097152

typedef uint32_t u32;
typedef unsigned short u16;
using f32x4 = __attribute__((ext_vector_type(4))) float;
using bfv8  = __attribute__((ext_vector_type(8))) short;
using bfv4  = __attribute__((ext_vector_type(4))) short;

#if __has_builtin(__builtin_amdgcn_mfma_f32_16x16x16bf16_1k)
#define HAS16 1
#else
#define HAS16 0
#endif

__device__ __forceinline__ u16 f2bf(float f){
  union { float f; u32 u; } v; v.f = f;
  u32 u = v.u;
  u32 r = (u + 0x7fffu + ((u >> 16) & 1u)) >> 16;
  return (u16)r;
}

__device__ __forceinline__ float bf2f(u16 h){
  union { u32 u; float f; } v; v.u = ((u32)h) << 16; return v.f;
}

__device__ __forceinline__ f32x4 mfma16(bfv8 a, bfv8 b, f32x4 c){
  return __builtin_amdgcn_mfma_f32_16x16x32_bf16(a, b, c, 0, 0, 0);
}

__device__ __forceinline__ u32 cvtpk(float a, float b){
  u32 r; asm("v_cvt_pk_bf16_f32 %0, %1, %2" : "=v"(r) : "v"(a), "v"(b)); return r;
}

__device__ __forceinline__ float fexp2(float x){
#if __has_builtin(__builtin_amdgcn_exp2f)
  return __builtin_amdgcn_exp2f(x);
#else
  return exp2f(x);
#endif
}

// async global->LDS, 16B per lane; lds dst is wave-uniform base (+lane*16 implicit)
__device__ __forceinline__ void gload16(const void* g, void* l){
  __builtin_amdgcn_global_load_lds((const __attribute__((address_space(1))) unsigned int*)g,
                                   (__attribute__((address_space(3))) unsigned int*)l, 16, 0, 0);
}

// ---------------- K0: key (B,C,HW) f32 -> keyT (B,HW,C) bf16, LDS tile transpose ----------------
__global__ __launch_bounds__(256) void k0_keyt(const float* __restrict__ key, u16* __restrict__ keyT){
  __shared__ u16 sm[64][73];
  int blk = blockIdx.x;             // 2048 = b + 8*(ct + 4*nt)
  int b = blk & 7; int r = blk >> 3; int ct = r & 3; int nt = r >> 2;
  int n0 = nt*64, c0 = ct*64;
  int t = threadIdx.x; int nl = t & 63; int cl0 = t >> 6;
#pragma unroll
  for (int i = 0; i < 16; ++i){
    int cl = i*4 + cl0;
    sm[cl][nl] = f2bf(key[(size_t)(b*CC + c0 + cl)*NHW + n0 + nl]);
  }
  __syncthreads();
#pragma unroll
  for (int i = 0; i < 2; ++i){
    int j = i*256 + t; int nl2 = j >> 3; int c8 = j & 7;
    __align__(16) u16 tmp[8];
#pragma unroll
    for (int k = 0; k < 8; ++k) tmp[k] = sm[c8*8 + k][nl2];
    *(uint4*)&keyT[(size_t)(b*NHW + n0 + nl2)*CC + c0 + c8*8] = *(uint4*)tmp;
  }
}

// ---------------- K0b: weights -> bf16, zero stats + protos ----------------
__global__ __launch_bounds__(256) void k0b_w(const float* __restrict__ Wth, const float* __restrict__ Wph,
                                             const float* __restrict__ Wg, const float* __restrict__ Wpc,
                                             const float* __restrict__ Wo,
                                             u16* __restrict__ Wbf, u16* __restrict__ Wobf,
                                             float* __restrict__ stats, float* __restrict__ protos){
  int flat = blockIdx.x*256 + threadIdx.x;
  if (flat < 1540) stats[flat] = 0.f;
  if (flat < BB*MM*HDIM) protos[flat] = 0.f;
  int base = flat*4;
  u16 o4[4]; uint2 pk;
  if (base < 512*256){
    int o = base >> 8, c = base & 255;
    const float* srcs[4] = {Wth, Wph, Wg, Wpc};
    const float* sp = srcs[o >> 7] + (size_t)(o & 127)*256 + c;
#pragma unroll
    for (int j=0;j<4;++j) o4[j] = f2bf(sp[j]);
    pk.x = (u32)o4[0] | ((u32)o4[1]<<16); pk.y = (u32)o4[2] | ((u32)o4[3]<<16);
    *(uint2*)&Wbf[base] = pk;
  } else {
    int b2 = base - 512*256;           // Wobf flat, 256*128
    const float* sp = Wo + b2;
#pragma unroll
    for (int j=0;j<4;++j) o4[j] = f2bf(sp[j]);
    pk.x = (u32)o4[0] | ((u32)o4[1]<<16); pk.y = (u32)o4[2] | ((u32)o4[3]<<16);
    *(uint2*)&Wobf[b2] = pk;
  }
}

// ---------------- K1: fused 4-conv MFMA GEMM, 4 waves (2n x 2ob), W prefetch ----------------
// theta output pre-scaled by log2(e) so k3 can use exp2.
__global__ __launch_bounds__(256) void k1_conv4(const u16* __restrict__ keyT, const u16* __restrict__ Wbf,
    const float* __restrict__ bth, const float* __restrict__ bph, const float* __restrict__ bg, const float* __restrict__ bpc,
    u16* __restrict__ thetaT, u16* __restrict__ phiT, u16* __restrict__ gN, float* __restrict__ pcraw)
{
  __shared__ __align__(16) u16 lds[64*256];     // 32KB, 16B-word swizzled: phys = logical ^ (row&7)
  int blk = blockIdx.x;                          // b + 8*nt, grid 512
  int b = blk & 7; int nt = blk >> 3; int n0 = nt*64;
  int t = threadIdx.x; int w = t >> 6; int l = t & 63;
  int l15 = l & 15, l4 = l >> 4;
  const u16* src = keyT + (size_t)(b*NHW + n0)*CC;
#pragma unroll
  for (int i = 0; i < 8; ++i){
    int c = w*8 + i;
    int row = c*2 + (l >> 5);
    int wl = (l & 31) ^ (row & 7);
    gload16(src + (size_t)row*256 + wl*8, &lds[c*512]);
  }
  __syncthreads();
  int wn = w & 1, wo = w >> 1;
  bfv8 a[2][8];
#pragma unroll
  for (int nb = 0; nb < 2; ++nb)
#pragma unroll
    for (int kb = 0; kb < 8; ++kb){
      int row = wn*32 + nb*16 + l15;
      int wd = (kb*4 + l4) ^ (row & 7);
      a[nb][kb] = *(const bfv8*)&lds[row*256 + wd*8];
    }
  const float* bias[4] = {bth, bph, bg, bpc};
  const u16* wpbase = Wbf + (size_t)(wo*16*16 + l15)*256 + l4*8;
  bfv8 wc[8], wnx[8];
#pragma unroll
  for (int kb = 0; kb < 8; ++kb) wc[kb] = *(const bfv8*)&wpbase[kb*32];
  for (int ob = 0; ob < 16; ++ob){
    if (ob < 15){
      const u16* wp = wpbase + (size_t)(ob+1)*16*256;
#pragma unroll
      for (int kb = 0; kb < 8; ++kb) wnx[kb] = *(const bfv8*)&wp[kb*32];
    }
    f32x4 acc[2] = {{0,0,0,0},{0,0,0,0}};
#pragma unroll
    for (int kb = 0; kb < 8; ++kb){
      acc[0] = mfma16(a[0][kb], wc[kb], acc[0]);
      acc[1] = mfma16(a[1][kb], wc[kb], acc[1]);
    }
    int obg = wo*16 + ob;
    int seg = obg >> 3;
    int oo = (obg & 7)*16 + l15;
    float bv = bias[seg][oo];
#pragma unroll
    for (int nb = 0; nb < 2; ++nb)
#pragma unroll
      for (int rr = 0; rr < 4; ++rr){
        int n = n0 + wn*32 + nb*16 + l4*4 + rr;
        float v = acc[nb][rr] + bv;
        size_t off = ((size_t)(b*NHW + n))*HDIM + oo;
        if      (seg == 0) thetaT[off] = f2bf(v * 1.44269504f);
        else if (seg == 1) phiT[off]   = f2bf(v);
        else if (seg == 2) gN[off]     = f2bf(v);
        else               pcraw[off]  = v;
      }
#pragma unroll
    for (int kb = 0; kb < 8; ++kb) wc[kb] = wnx[kb];
  }
}

// ---------------- K1b: gN (B,HW,HD) -> gT (B,HD,HW) bf16 ----------------
__global__ __launch_bounds__(256) void k1b_gt(const u16* __restrict__ gN, u16* __restrict__ gT){
  __shared__ __align__(16) u16 lds[64][72];
  int blk = blockIdx.x;               // 1024 = b + 8*(nt + 64*dt)
  int b = blk & 7; int r = blk >> 3; int nt = r & 63; int dt = r >> 6;
  int n0 = nt*64, d0 = dt*64;
  int t = threadIdx.x;
#pragma unroll
  for (int i = 0; i < 2; ++i){
    int seg = i*256 + t; int row = seg >> 3; int sg = seg & 7;
    *(uint4*)&lds[row][sg*8] = *(const uint4*)&gN[(size_t)(b*NHW + n0 + row)*HDIM + d0 + sg*8];
  }
  __syncthreads();
  int dr = t >> 2, ns = (t & 3)*16;
  __align__(16) u16 tmp[16];
#pragma unroll
  for (int j = 0; j < 16; ++j) tmp[j] = lds[ns + j][dr];
  u16* dst = gT + (size_t)(b*HDIM + d0 + dr)*NHW + n0 + ns;
  *(uint4*)&dst[0] = *(uint4*)&tmp[0];
  *(uint4*)&dst[8] = *(uint4*)&tmp[8];
}

// ---------------- K2: pc BN stats ----------------
__global__ __launch_bounds__(256) void k2_pcstats(const float* __restrict__ pcraw, float* __restrict__ stats){
  int blk = blockIdx.x;                // 256 = b*32 + ch
  int b = blk >> 5; int ch = blk & 31; int n0 = ch*128;
  int t = threadIdx.x; int d = t & 127; int j = t >> 7;
  float s = 0, ss = 0;
  const float* p = pcraw + (size_t)(b*NHW + n0)*HDIM;
  for (int i = 0; i < 64; ++i){ float v = p[(size_t)(i*2 + j)*HDIM + d]; s += v; ss += v*v; }
  __shared__ float red[2][256];
  red[0][t] = s; red[1][t] = ss;
  __syncthreads();
  if (t < 128){
    atomicAdd(&stats[d],       red[0][t] + red[0][t+128]);
    atomicAdd(&stats[128 + d], red[1][t] + red[1][t+128]);
  }
}

// ---------------- K2b: keyf = relu(BN(pcraw)) — BN params computed inline ----------------
__global__ __launch_bounds__(256) void k2b_keyf(const float* __restrict__ pcraw, const float* __restrict__ stats,
                                                const float* __restrict__ gamma, const float* __restrict__ beta,
                                                float* __restrict__ keyf){
  int idx = blockIdx.x*256 + threadIdx.x;
  int base = idx*4; int d0 = base & 127;
  f32x4 v = *(const f32x4*)&pcraw[base];
  f32x4 o;
#pragma unroll
  for (int j = 0; j < 4; ++j){
    int d = d0 + j;
    float mean = stats[d] * (1.f/32768.f);
    float var  = stats[128+d] * (1.f/32768.f) - mean*mean;
    if (var < 0.f) var = 0.f;
    float rstd = rsqrtf(var + 1e-5f);
    float x = (v[j] - mean) * rstd * gamma[d] + beta[d];
    o[j] = x > 0.f ? x : 0.f;
  }
  *(f32x4*)&keyf[base] = o;
}

// ---------------- K3: flash attention v4 ----------------
// 64 q/wave (256 q/block), swapped QK (mfma(K,Q)) so each lane holds 4 consecutive m per q;
// P packed in-register via v_cvt_pk_bf16_f32 and fed to 16x16x16 PV MFMA (no P LDS).
// fixed-max softmax via exp2 (theta pre-scaled by log2 e); KV-split=4; double-buffered K/V.
__global__ __launch_bounds__(256, 2) void k3_attn(const u16* __restrict__ thetaT, const u16* __restrict__ phiT,
                                               const u16* __restrict__ gT,
                                               u16* __restrict__ nl0, u16* __restrict__ nl1,
                                               u16* __restrict__ nl2, u16* __restrict__ nl3,
                                               float* __restrict__ lsumP){
  __shared__ __align__(16) u16 K2[2][32*128];   // 2 x 8KB, m-major rows 256B, slot^ (row&7) swizzle
  __shared__ __align__(16) u16 V2[2][128*32];   // 2 x 8KB, d-major rows 64B, slot^(row&3) swizzle
#if !HAS16
  __shared__ __align__(16) u16 P[4][64*40];     // fallback P: per wave 64q x 32m pad 40
#endif
  int blk = blockIdx.x;             // b + 8*(qt + 16*split); b = XCD id
  int b = blk & 7; int qt = (blk >> 3) & 15; int split = blk >> 7;
  int n0 = qt*256;
  int t = threadIdx.x; int w = t >> 6; int l = t & 63;
  int l15 = l & 15, l4 = l >> 4;
  // Q fragments (B operand): qf[qb][kb]
  bfv8 qf[4][4];
#pragma unroll
  for (int qb = 0; qb < 4; ++qb){
    const u16* qp = thetaT + (size_t)(b*NHW + n0 + w*64 + qb*16 + l15)*HDIM + l4*8;
#pragma unroll
    for (int kb = 0; kb < 4; ++kb) qf[qb][kb] = *(const bfv8*)&qp[kb*32];
  }
  float lsum[4];
  f32x4 acco[4][8];
#pragma unroll
  for (int qb = 0; qb < 4; ++qb){
    lsum[qb] = 0.f;
#pragma unroll
    for (int db = 0; db < 8; ++db) acco[qb][db] = {0,0,0,0};
  }
  const u16* Kg = phiT + (size_t)b*NHW*HDIM;
  const u16* Vg = gT   + (size_t)b*HDIM*NHW;
  int mt0 = split*32;               // 32 tiles of 32 m each

#define STAGE(bf, mt) {                                                        \
    int m0 = (mt)*32;                                                          \
  _Pragma("unroll")                                                            \
    for (int i = 0; i < 2; ++i){                                               \
      int c = w*2 + i;                                                         \
      int row = c*4 + (l >> 4);                                                \
      int wl = (l & 15) ^ (row & 7);                                           \
      gload16(Kg + (size_t)(m0 + row)*HDIM + wl*8, &K2[bf][c*512]);            \
    }                                                                          \
  _Pragma("unroll")                                                            \
    for (int i = 0; i < 2; ++i){                                               \
      int c = w*2 + i;                                                         \
      int row = c*16 + (l >> 2);                                               \
      int wl = (l & 3) ^ (row & 3);                                            \
      gload16(Vg + (size_t)row*NHW + m0 + wl*8, &V2[bf][c*512]);               \
    }                                                                          \
  }

  STAGE(0, mt0);
  __syncthreads();
  int cur = 0;
  for (int it = 0; it < 32; ++it){
    if (it < 31) STAGE(cur^1, mt0 + it + 1);
    // QK^T swapped: A=K (rows m), B=Q (cols q) -> lane holds P[q=l15][m = mb*16 + l4*4 + rr]
    f32x4 s[2][4];
#pragma unroll
    for (int mb = 0; mb < 2; ++mb)
#pragma unroll
      for (int qb = 0; qb < 4; ++qb) s[mb][qb] = {0,0,0,0};
    __builtin_amdgcn_s_setprio(1);
#pragma unroll
    for (int kb = 0; kb < 4; ++kb){
#pragma unroll
      for (int mb = 0; mb < 2; ++mb){
        int krow = mb*16 + l15;
        int kw = (kb*4 + l4) ^ (krow & 7);
        bfv8 kf = *(const bfv8*)&K2[cur][krow*128 + kw*8];
#pragma unroll
        for (int qb = 0; qb < 4; ++qb)
          s[mb][qb] = mfma16(kf, qf[qb][kb], s[mb][qb]);
      }
    }
    __builtin_amdgcn_s_setprio(0);
#if HAS16
    // softmax: p = exp2(s); pack 4 consecutive m into bf16x4 (A-frag of 16x16x16 MFMA)
    bfv4 pa[2][4];
#pragma unroll
    for (int mb = 0; mb < 2; ++mb)
#pragma unroll
      for (int qb = 0; qb < 4; ++qb){
        float p0 = fexp2(s[mb][qb][0]);
        float p1 = fexp2(s[mb][qb][1]);
        float p2 = fexp2(s[mb][qb][2]);
        float p3 = fexp2(s[mb][qb][3]);
        lsum[qb] += (p0+p1)+(p2+p3);
        union { uint2 u; bfv4 v; } cv;
        cv.u.x = cvtpk(p0, p1); cv.u.y = cvtpk(p2, p3);
        pa[mb][qb] = cv.v;
      }
    // PV: A=P (rows q, k=m), B=V (cols d, k=m), K=16 per mfma
    __builtin_amdgcn_s_setprio(1);
#pragma unroll
    for (int db = 0; db < 8; ++db){
      int vrow = db*16 + l15;
#pragma unroll
      for (int mb = 0; mb < 2; ++mb){
        int sg = mb*2 + (l4 >> 1);
        int ph = ((sg ^ (vrow & 3))*8 + (l4 & 1)*4);
        bfv4 vf = *(const bfv4*)&V2[cur][vrow*32 + ph];
#pragma unroll
        for (int qb = 0; qb < 4; ++qb)
          acco[qb][db] = __builtin_amdgcn_mfma_f32_16x16x16bf16_1k(pa[mb][qb], vf, acco[qb][db], 0, 0, 0);
      }
    }
    __builtin_amdgcn_s_setprio(0);
#else
    // fallback: P through per-wave LDS, PV with 16x16x32
    u16* Pw = &P[w][0];
#pragma unroll
    for (int mb = 0; mb < 2; ++mb)
#pragma unroll
      for (int qb = 0; qb < 4; ++qb){
        float p0 = fexp2(s[mb][qb][0]);
        float p1 = fexp2(s[mb][qb][1]);
        float p2 = fexp2(s[mb][qb][2]);
        float p3 = fexp2(s[mb][qb][3]);
        lsum[qb] += (p0+p1)+(p2+p3);
        uint2 pk; pk.x = cvtpk(p0, p1); pk.y = cvtpk(p2, p3);
        *(uint2*)&Pw[(qb*16 + l15)*40 + mb*16 + l4*4] = pk;
      }
    bfv8 pa[4];
#pragma unroll
    for (int qb = 0; qb < 4; ++qb)
      pa[qb] = *(const bfv8*)&Pw[(qb*16 + l15)*40 + l4*8];
    __builtin_amdgcn_s_setprio(1);
#pragma unroll
    for (int db = 0; db < 8; ++db){
      int vrow = db*16 + l15;
      int vw = l4 ^ (vrow & 3);
      bfv8 vf = *(const bfv8*)&V2[cur][vrow*32 + vw*8];
#pragma unroll
      for (int qb = 0; qb < 4; ++qb)
        acco[qb][db] = mfma16(pa[qb], vf, acco[qb][db]);
    }
    __builtin_amdgcn_s_setprio(0);
#endif
    __syncthreads();                   // drains vmcnt -> staged buf ready; protects buf reuse
    cur ^= 1;
  }
#undef STAGE
  // epilogue: lsum per q = l15-lane; sum across the 4 quarters; write bf16 partial O + lsum
  u16* nlsaP = (split==0) ? nl0 : (split==1) ? nl1 : (split==2) ? nl2 : nl3;
#pragma unroll
  for (int qb = 0; qb < 4; ++qb){
    float v = lsum[qb];
    v += __shfl_xor(v, 16); v += __shfl_xor(v, 32);
    if (l < 16) lsumP[(size_t)(split*8 + b)*NHW + n0 + w*64 + qb*16 + l] = v;
#pragma unroll
    for (int rr = 0; rr < 4; ++rr){
      int n = n0 + w*64 + qb*16 + l4*4 + rr;
      u16* op = nlsaP + ((size_t)(b*NHW + n))*HDIM;
#pragma unroll
      for (int db = 0; db < 8; ++db)
        op[db*16 + l15] = f2bf(acco[qb][db][rr]);
    }
  }
}

// ---------------- K4: protos (unnormalized; softmax normalizer cancels in l2norm) ----------------
__global__ __launch_bounds__(256) void k4_protos(const float* __restrict__ keyf, const float* __restrict__ Wh,
                                                 float* __restrict__ protos){
  __shared__ float wh[10][128];
  __shared__ float e[128][12];
  __shared__ float pacc[10][128];
  int blk = blockIdx.x; int b = blk & 7; int ns = blk >> 3;   // 32 ns
  int n0 = ns*128;
  int t = threadIdx.x;
  for (int i = t; i < 1280; i += 256) wh[i>>7][i&127] = Wh[i];
  __syncthreads();
  const float* kf = keyf + ((size_t)b*NHW + n0)*HDIM;
  {
    int nn = t >> 1; int mh = (t & 1)*5;
    const f32x4* row = (const f32x4*)&kf[(size_t)nn*HDIM];
    float s5[5];
#pragma unroll
    for (int m = 0; m < 5; ++m) s5[m] = 0.f;
    for (int d4 = 0; d4 < 32; ++d4){
      f32x4 kv = row[d4];
#pragma unroll
      for (int m = 0; m < 5; ++m){
        f32x4 wv = *(const f32x4*)&wh[mh+m][d4*4];
        s5[m] += kv[0]*wv[0] + kv[1]*wv[1] + kv[2]*wv[2] + kv[3]*wv[3];
      }
    }
#pragma unroll
    for (int m = 0; m < 5; ++m) e[nn][mh+m] = __expf(s5[m]);
  }
  __syncthreads();
  int d = t & 127, j = t >> 7;
  float acc[10];
#pragma unroll
  for (int m = 0; m < 10; ++m) acc[m] = 0.f;
  for (int i = 0; i < 64; ++i){
    int n = j*64 + i;
    float kv = kf[(size_t)n*HDIM + d];
#pragma unroll
    for (int m = 0; m < 10; ++m) acc[m] += e[n][m]*kv;
  }
  if (j == 1){
#pragma unroll
    for (int m = 0; m < 10; ++m) pacc[m][d] = acc[m];
  }
  __syncthreads();
  if (j == 0){
#pragma unroll
    for (int m = 0; m < 10; ++m)
      atomicAdd(&protos[(size_t)(b*MM + m)*HDIM + d], acc[m] + pacc[m][d]);
  }
}

// ---------------- K5: normalize protos -> pnorm (own batch) + dis/cst losses ----------------
__global__ __launch_bounds__(128) void k5_pnloss(const float* __restrict__ protos, float* __restrict__ pnorm,
                                                 float* __restrict__ stats){
  __shared__ float pr[20][128];
  __shared__ float rd[2][2];
  int b = blockIdx.x;                // 8
  int t = threadIdx.x; int wv = t >> 6; int ln = t & 63;
  int nrows = (b < 7) ? 20 : 10;
  for (int r = wv; r < nrows; r += 2){
    int g = (r < 10) ? (b*10 + r) : ((b+1)*10 + (r-10));
    float v0 = protos[g*128 + ln];
    float v1 = protos[g*128 + 64 + ln];
    float ss = v0*v0 + v1*v1;
#pragma unroll
    for (int msk = 1; msk < 64; msk <<= 1) ss += __shfl_xor(ss, msk);
    float inv = 1.f / fmaxf(sqrtf(ss), 1e-12f);
    v0 *= inv; v1 *= inv;
    pr[r][ln] = v0; pr[r][64+ln] = v1;
    if (r < 10){ pnorm[g*128 + ln] = v0; pnorm[g*128 + 64 + ln] = v1; }
  }
  __syncthreads();
  int d = t;                         // 0..127
  float dacc = 0.f;
#pragma unroll
  for (int m1 = 0; m1 < 10; ++m1){
    float a = pr[m1][d];
#pragma unroll
    for (int m2 = 0; m2 < 10; ++m2){
      if (d >= m2 + 1){
        float df = a - pr[m2][d];
        float v = 1.f - df*df;
        if (v > 0.f) dacc += v;
      }
    }
  }
  float cacc = 0.f;
  if (b < 7){
#pragma unroll
    for (int m = 0; m < 10; ++m){
      float df = pr[10+m][d] - pr[m][d];
      cacc += df*df;
    }
  }
#pragma unroll
  for (int msk = 1; msk < 64; msk <<= 1){ dacc += __shfl_xor(dacc, msk); cacc += __shfl_xor(cacc, msk); }
  if (ln == 0){ rd[0][wv] = dacc; rd[1][wv] = cacc; }
  __syncthreads();
  if (t == 0){
    atomicAdd(&stats[1537], rd[0][0] + rd[0][1]);
    atomicAdd(&stats[1538], rd[1][0] + rd[1][1]);
  }
}

// ---------------- K6: score softmax, new_q, combine 4 nlsa splits (bf16), uq bf16, fea ----------------
// Streaming three-pass (round-4 proven form): keyf row re-read per pass (L2-resident), no big
// per-thread arrays -> no scratch spill.
__global__ __launch_bounds__(64) void k6_newq(const float* __restrict__ keyf, const float* __restrict__ pn,
                                              const u16* __restrict__ nl0, const u16* __restrict__ nl1,
                                              const u16* __restrict__ nl2, const u16* __restrict__ nl3,
                                              const float* __restrict__ lsumP,
                                              u16* __restrict__ uqbf, float* __restrict__ fea_acc){
  __shared__ float pnl[10][128];
  int blk = blockIdx.x;              // 512 = b + 8*nt
  int b = blk & 7; int nt = blk >> 3;
  int t = threadIdx.x;
  for (int i = t; i < 1280; i += 64) pnl[i>>7][i&127] = pn[(size_t)b*1280 + i];
  __syncthreads();
  int n = nt*64 + t;
  const float* kf = keyf + (size_t)(b*NHW + n)*HDIM;
  float s[10];
#pragma unroll
  for (int m = 0; m < 10; ++m) s[m] = 0;
  for (int d4 = 0; d4 < 32; ++d4){
    f32x4 kv = *(const f32x4*)&kf[d4*4];
#pragma unroll
    for (int m = 0; m < 10; ++m){
      f32x4 pv = *(const f32x4*)&pnl[m][d4*4];
      s[m] += kv[0]*pv[0]+kv[1]*pv[1]+kv[2]*pv[2]+kv[3]*pv[3];
    }
  }
  float mx = s[0]; int idx = 0;
#pragma unroll
  for (int m = 1; m < 10; ++m) if (s[m] > mx){ mx = s[m]; idx = m; }
  float S_ = 0, sp[10];
#pragma unroll
  for (int m = 0; m < 10; ++m){ float ev = __expf(s[m]-mx); sp[m] = ev; S_ += ev; }
  float invS = 1.f/S_;
#pragma unroll
  for (int m = 0; m < 10; ++m) sp[m] *= invS;
  float ssq = 0, fea = 0;
  for (int d4 = 0; d4 < 32; ++d4){
    f32x4 kv = *(const f32x4*)&kf[d4*4];
    f32x4 a = {0,0,0,0};
#pragma unroll
    for (int m = 0; m < 10; ++m){
      f32x4 pv = *(const f32x4*)&pnl[m][d4*4];
      a[0] += sp[m]*pv[0]; a[1] += sp[m]*pv[1]; a[2] += sp[m]*pv[2]; a[3] += sp[m]*pv[3];
    }
    ssq += a[0]*a[0]+a[1]*a[1]+a[2]*a[2]+a[3]*a[3];
    f32x4 pb = *(const f32x4*)&pnl[idx][d4*4];
    float e0 = kv[0]-pb[0], e1 = kv[1]-pb[1], e2 = kv[2]-pb[2], e3 = kv[3]-pb[3];
    fea += e0*e0+e1*e1+e2*e2+e3*e3;
  }
  float inv = 1.f / fmaxf(sqrtf(ssq), 1e-12f);
  float ls = lsumP[(size_t)b*NHW + n] + lsumP[(size_t)(8+b)*NHW + n]
           + lsumP[(size_t)(16+b)*NHW + n] + lsumP[(size_t)(24+b)*NHW + n];
  float invl = 1.f/ls;
  const u16* na0 = nl0 + (size_t)(b*NHW + n)*HDIM;
  const u16* na1 = nl1 + (size_t)(b*NHW + n)*HDIM;
  const u16* na2 = nl2 + (size_t)(b*NHW + n)*HDIM;
  const u16* na3 = nl3 + (size_t)(b*NHW + n)*HDIM;
  u16* uo = uqbf + (size_t)(b*NHW + n)*HDIM;
  for (int d4 = 0; d4 < 32; ++d4){
    f32x4 a = {0,0,0,0};
#pragma unroll
    for (int m = 0; m < 10; ++m){
      f32x4 pv = *(const f32x4*)&pnl[m][d4*4];
      a[0] += sp[m]*pv[0]; a[1] += sp[m]*pv[1]; a[2] += sp[m]*pv[2]; a[3] += sp[m]*pv[3];
    }
    uint2 r0 = *(const uint2*)&na0[d4*4];
    uint2 r1 = *(const uint2*)&na1[d4*4];
    uint2 r2 = *(const uint2*)&na2[d4*4];
    uint2 r3 = *(const uint2*)&na3[d4*4];
    u16 o4[4];
#pragma unroll
    for (int j = 0; j < 4; ++j){
      u32 word0 = (j < 2) ? r0.x : r0.y;  u32 word1 = (j < 2) ? r1.x : r1.y;
      u32 word2 = (j < 2) ? r2.x : r2.y;  u32 word3 = (j < 2) ? r3.x : r3.y;
      int sh = (j & 1)*16;
      float nv = bf2f((u16)(word0 >> sh)) + bf2f((u16)(word1 >> sh))
               + bf2f((u16)(word2 >> sh)) + bf2f((u16)(word3 >> sh));
      o4[j] = f2bf(a[j]*inv + nv*invl);
    }
    uint2 pk; pk.x = (u32)o4[0] | ((u32)o4[1]<<16); pk.y = (u32)o4[2] | ((u32)o4[3]<<16);
    *(uint2*)&uo[d4*4] = pk;
  }
#pragma unroll
  for (int msk = 1; msk < 64; msk <<= 1) fea += __shfl_xor(fea, msk);
  if (t == 0) atomicAdd(fea_acc, fea);
}

// ---------------- K7: conv_o MFMA GEMM -> convo bf16 ----------------
__global__ __launch_bounds__(256) void k7_convo(const u16* __restrict__ uqbf, const u16* __restrict__ Wobf,
                                                const float* __restrict__ bo, u16* __restrict__ convo){
  __shared__ __align__(16) u16 lds[64*128];      // 16KB swizzled
  int blk = blockIdx.x;                          // b + 8*nt, grid 512
  int b = blk & 7; int nt = blk >> 3; int n0 = nt*64;
  int t = threadIdx.x; int w = t >> 6; int l = t & 63; int l15 = l&15, l4 = l>>4;
  const u16* src = uqbf + (size_t)(b*NHW + n0)*HDIM;
#pragma unroll
  for (int i = 0; i < 4; ++i){
    int c = w*4 + i;
    int row = c*4 + (l >> 4);
    int wl = (l & 15) ^ (row & 7);
    gload16(src + (size_t)row*128 + wl*8, &lds[c*512]);
  }
  __syncthreads();
  int wn = w & 1, wo = w >> 1;
  bfv8 a[2][4];
#pragma unroll
  for (int nb = 0; nb < 2; ++nb)
#pragma unroll
    for (int kb = 0; kb < 4; ++kb){
      int row = wn*32 + nb*16 + l15;
      int wd = (kb*4 + l4) ^ (row & 7);
      a[nb][kb] = *(const bfv8*)&lds[row*128 + wd*8];
    }
  const u16* wpbase = Wobf + (size_t)(wo*8*16 + l15)*128 + l4*8;
  bfv8 wc[4], wnx[4];
#pragma unroll
  for (int kb = 0; kb < 4; ++kb) wc[kb] = *(const bfv8*)&wpbase[kb*32];
  for (int ob = 0; ob < 8; ++ob){
    if (ob < 7){
      const u16* wp = wpbase + (size_t)(ob+1)*16*128;
#pragma unroll
      for (int kb = 0; kb < 4; ++kb) wnx[kb] = *(const bfv8*)&wp[kb*32];
    }
    f32x4 acc[2] = {{0,0,0,0},{0,0,0,0}};
#pragma unroll
    for (int kb = 0; kb < 4; ++kb){
      acc[0] = mfma16(a[0][kb], wc[kb], acc[0]);
      acc[1] = mfma16(a[1][kb], wc[kb], acc[1]);
    }
    int obg = wo*8 + ob;
    int oc = obg*16 + l15;
    float bv = bo[oc];
#pragma unroll
    for (int nb = 0; nb < 2; ++nb)
#pragma unroll
      for (int rr = 0; rr < 4; ++rr){
        int n = n0 + wn*32 + nb*16 + l4*4 + rr;
        convo[(size_t)(b*NHW + n)*CC + oc] = f2bf(acc[nb][rr] + bv);
      }
#pragma unroll
    for (int kb = 0; kb < 4; ++kb) wc[kb] = wnx[kb];
  }
}

// ---------------- K8: conv_o BN stats (bf16 in) ----------------
__global__ __launch_bounds__(256) void k8_ostats(const u16* __restrict__ convo, float* __restrict__ stats){
  int blk = blockIdx.x;                // 256 = b*32 + ch
  int b = blk >> 5; int ch = blk & 31; int n0 = ch*128;
  int t = threadIdx.x;
  float s = 0, ss = 0;
  const u16* p = convo + (size_t)(b*NHW + n0)*CC;
  for (int i = 0; i < 128; ++i){ float v = bf2f(p[(size_t)i*CC + t]); s += v; ss += v*v; }
  atomicAdd(&stats[512 + t], s);
  atomicAdd(&stats[768 + t], ss);
}

__global__ void k8a_fin(float* stats, float* dout){  // 256 threads
  int c = threadIdx.x;
  float mean = stats[512+c] * (1.f/32768.f);
  float var  = stats[768+c] * (1.f/32768.f) - mean*mean;
  if (var < 0.f) var = 0.f;
  stats[1024+c] = mean;
  stats[1280+c] = rsqrtf(var + 1e-5f);
  if (c == 0){
    dout[OUTN]   = stats[1536] * (1.f/4194304.f);
    dout[OUTN+1] = stats[1538] * (1.f/70.f);
    dout[OUTN+2] = stats[1537] * (2.f/90.f) * (1.f/1280.f);
  }
}

// ---------------- K9: out = relu(BN(convo)) + query (bf16 convo in) ----------------
__global__ __launch_bounds__(256) void k9_out(const u16* __restrict__ convo, const float* __restrict__ stats,
                                              const float* __restrict__ gamma, const float* __restrict__ beta,
                                              const float* __restrict__ query, float* __restrict__ dout){
  __shared__ __align__(16) float lds[32*260];
  int blk = blockIdx.x; int b = blk & 7; int nt = blk >> 3; int n0 = nt*32;
  int t = threadIdx.x;
  const u16* src = convo + (size_t)(b*NHW + n0)*CC;
#pragma unroll
  for (int i = 0; i < 4; ++i){
    int seg = i*256 + t; int row = seg >> 5; int sg = seg & 31;
    uint4 pk = *(const uint4*)&src[(size_t)row*CC + sg*8];
    float* dst = &lds[row*260 + sg*8];
    u32 ws[4] = {pk.x, pk.y, pk.z, pk.w};
#pragma unroll
    for (int j = 0; j < 4; ++j){
      dst[j*2]   = bf2f((u16)(ws[j] & 0xffffu));
      dst[j*2+1] = bf2f((u16)(ws[j] >> 16));
    }
  }
  __syncthreads();
  int nn = t & 31, og = t >> 5;
  for (int i = 0; i < 32; ++i){
    int oc = og*32 + i;
    float v = lds[nn*260 + oc];
    v = (v - stats[1024+oc]) * stats[1280+oc] * gamma[oc] + beta[oc];
    v = fmaxf(v, 0.f);
    size_t off = (size_t)(b*CC + oc)*NHW + n0 + nn;
    dout[off] = v + query[off];
  }
}

// ---------------- launch ----------------
extern "C" void kernel_launch(void* const* d_in, const int* in_sizes, int n_in,
                              void* d_out, int out_size, void* d_ws, size_t ws_size,
                              hipStream_t stream) {
  const float* key   = (const float*)d_in[0];
  const float* query = (const float*)d_in[1];
  const float* Wth = (const float*)d_in[2];
  const float* bth = (const float*)d_in[3];
  const float* Wph = (const float*)d_in[4];
  const float* bph = (const float*)d_in[5];
  const float* Wg  = (const float*)d_in[6];
  const float* bg  = (const float*)d_in[7];
  const float* Wpc = (const float*)d_in[8];
  const float* bpc = (const float*)d_in[9];
  const float* gpc = (const float*)d_in[10];
  const float* bepc= (const float*)d_in[11];
  const float* Wh  = (const float*)d_in[12];
  const float* Wo  = (const float*)d_in[13];
  const float* bo  = (const float*)d_in[14];
  const float* go  = (const float*)d_in[15];
  const float* beo = (const float*)d_in[16];

  char* ws = (char*)d_ws;
  u16*   keyT   = (u16*)  (ws + 0);          // 16MB [k0->k1]
  u16*   nlsa0  = (u16*)  (ws + 0);          // 8MB [k3->k6] (reuses keyT)
  u16*   nlsa1  = (u16*)  (ws + 8388608);    // 8MB [k3->k6]
  u16*   thetaT = (u16*)  (ws + 16777216);   // 8MB
  u16*   phiT   = (u16*)  (ws + 25165824);   // 8MB
  u16*   gN     = (u16*)  (ws + 33554432);   // 8MB [k1->k1b]
  float* lsum   = (float*)(ws + 33554432);   // 512KB [k3->k6] (reuses gN)
  u16*   gT     = (u16*)  (ws + 41943040);   // 8MB [k1b->k3]
  float* pcraw  = (float*)(ws + 50331648);   // 16MB [k1->k2b]
  u16*   nlsa2  = (u16*)  (ws + 50331648);   // 8MB [k3->k6] (reuses pcraw)
  u16*   nlsa3  = (u16*)  (ws + 58720256);   // 8MB [k3->k6]
  float* keyf   = (float*)(ws + 67108864);   // 16MB [k2b->k4,k6]
  u16*   uqbf   = (u16*)  (ws + 83886080);   // 8MB [k6->k7]
  u16*   convo  = (u16*)  (ws + 92274688);   // 16MB bf16 [k7->k8,k9]
  u16*   Wbf    = (u16*)  (ws + 109051904);  // 256KB
  u16*   Wobf   = (u16*)  (ws + 109314048);  // 64KB
  float* protos = (float*)(ws + 109379584);  // 40KB
  float* pnorm  = (float*)(ws + 109420544);  // 40KB
  float* stats  = (float*)(ws + 109461504);  // 8KB
  float* dout   = (float*)d_out;

  k0_keyt<<<2048,256,0,stream>>>(key, keyT);
  k0b_w<<<160,256,0,stream>>>(Wth, Wph, Wg, Wpc, Wo, Wbf, Wobf, stats, protos);
  k1_conv4<<<512,256,0,stream>>>(keyT, Wbf, bth, bph, bg, bpc, thetaT, phiT, gN, pcraw);
  k1b_gt<<<1024,256,0,stream>>>(gN, gT);
  k2_pcstats<<<256,256,0,stream>>>(pcraw, stats);
  k2b_keyf<<<4096,256,0,stream>>>(pcraw, stats, gpc, bepc, keyf);
  k3_attn<<<512,256,0,stream>>>(thetaT, phiT, gT, nlsa0, nlsa1, nlsa2, nlsa3, lsum);
  k4_protos<<<256,256,0,stream>>>(keyf, Wh, protos);
  k5_pnloss<<<8,128,0,stream>>>(protos, pnorm, stats);
  k6_newq<<<512,64,0,stream>>>(keyf, pnorm, nlsa0, nlsa1, nlsa2, nlsa3, lsum, uqbf, &stats[1536]);
  k7_convo<<<512,256,0,stream>>>(uqbf, Wobf, bo, convo);
  k8_ostats<<<256,256,0,stream>>>(convo, stats);
  k8a_fin<<<1,256,0,stream>>>(stats, dout);
  k9_out<<<1024,256,0,stream>>>(convo, stats, go, beo, query, dout);
}